// Round 7
// baseline (129.768 us; speedup 1.0000x reference)
//
#include <hip/hip_runtime.h>
#include <math.h>

#define D_MODEL 768
#define D_STATE 64
#define BATCH   2
#define SEQ     2048
#define M_TOTAL (BATCH * SEQ)   // 4096

typedef unsigned short ushort_t;
typedef float f32x4 __attribute__((ext_vector_type(4)));
typedef __bf16 bf16x8 __attribute__((ext_vector_type(8)));

__device__ __forceinline__ ushort_t f2bf(float f) {
    unsigned u = __float_as_uint(f);
    u = (u + 0x7FFFu + ((u >> 16) & 1u)) >> 16;   // RNE
    return (ushort_t)u;
}

__device__ __forceinline__ void gload16(const void* g, void* shm) {
    __builtin_amdgcn_global_load_lds(
        (const __attribute__((address_space(1))) void*)g,
        (__attribute__((address_space(3))) void*)shm, 16, 0, 0);
}

// ---------------- fused pre-kernel: LayerNorm->bf16 + weight casts ----------------
__global__ __launch_bounds__(256) void pre_kernel(const float* __restrict__ x,
                                                  const float* __restrict__ gamma,
                                                  const float* __restrict__ beta,
                                                  ushort_t* __restrict__ xnb,
                                                  const float* __restrict__ W_in,
                                                  const float* __restrict__ W_out,
                                                  ushort_t* __restrict__ Winb,
                                                  ushort_t* __restrict__ Woutb) {
    int bx = blockIdx.x;
    if (bx >= 1024) {
        int b2 = bx - 1024;
        const float* src = (b2 < 576) ? W_in : W_out;
        ushort_t*    dst = (b2 < 576) ? Winb : Woutb;
        int blk = (b2 < 576) ? b2 : b2 - 576;
        int i = (blk * 256 + threadIdx.x) * 4;
        float4 v = *(const float4*)(src + i);
        ushort4 o = make_ushort4(f2bf(v.x), f2bf(v.y), f2bf(v.z), f2bf(v.w));
        *(ushort4*)(dst + i) = o;
        return;
    }
    int row  = bx * 4 + (threadIdx.x >> 6);
    int lane = threadIdx.x & 63;
    const float* xr = x + (size_t)row * D_MODEL;
    float4 v[3];
    v[0] = *(const float4*)(xr + lane * 4);
    v[1] = *(const float4*)(xr + 256 + lane * 4);
    v[2] = *(const float4*)(xr + 512 + lane * 4);
    float s = 0.f, ss = 0.f;
#pragma unroll
    for (int i = 0; i < 3; ++i) {
        s  += v[i].x + v[i].y + v[i].z + v[i].w;
        ss += v[i].x * v[i].x + v[i].y * v[i].y + v[i].z * v[i].z + v[i].w * v[i].w;
    }
#pragma unroll
    for (int off = 1; off < 64; off <<= 1) {
        s  += __shfl_xor(s, off, 64);
        ss += __shfl_xor(ss, off, 64);
    }
    float mean = s * (1.0f / 768.0f);
    float var  = ss * (1.0f / 768.0f) - mean * mean;
    float inv  = 1.0f / sqrtf(var + 1e-5f);
    ushort_t* xo = xnb + (size_t)row * D_MODEL;
#pragma unroll
    for (int i = 0; i < 3; ++i) {
        int c = i * 256 + lane * 4;
        float4 g  = *(const float4*)(gamma + c);
        float4 bb = *(const float4*)(beta + c);
        ushort4 o = make_ushort4(f2bf((v[i].x - mean) * inv * g.x + bb.x),
                                 f2bf((v[i].y - mean) * inv * g.y + bb.y),
                                 f2bf((v[i].z - mean) * inv * g.z + bb.z),
                                 f2bf((v[i].w - mean) * inv * g.w + bb.w));
        *(ushort4*)(xo + c) = o;
    }
}

// ---------------- bf16 MFMA GEMM: block 128x96, wave-tile 64x48, BK=64 ----------------
// Grid 32x8 = 256 blocks = 1/CU. Double-buffered LDS, ONE barrier per K-iter:
//   barrier -> issue next-tile global_load_lds (async) -> ds_read+MFMA current -> barrier
// so the vmcnt(0) drain at the barrier covers loads issued a full compute phase earlier.
// LDS rows = 128B (64 bf16) = 8 segs of 16B, XOR-swizzled by row so fragment
// reads (16 rows, same logical seg) hit distinct banks (2-way max = free).
#define ABUF  16384            // 128 rows * 128B
#define BUFSZ 28672            // + 96 rows * 128B

__device__ __forceinline__ void gemm_core(const ushort_t* __restrict__ A,
                                          const ushort_t* __restrict__ B,
                                          const float* __restrict__ bias,
                                          char* smem, int tid, int bm, int bn,
                                          int w, int l, int wm, int wn,
                                          f32x4 acc[4][3], float biasv[3]) {
    int seg8 = ((l & 7) ^ (l >> 3)) * 8;
    const ushort_t* gA = A + (size_t)(bm + w * 32 + (l >> 3)) * D_MODEL + seg8;
    const ushort_t* gB = B + (size_t)(bn + w * 24 + (l >> 3)) * D_MODEL + seg8;
#pragma unroll
    for (int nt = 0; nt < 3; ++nt)
        biasv[nt] = bias[bn + wn + nt * 16 + (l & 15)];
    // prologue: stage buf0 (k=0)
#pragma unroll
    for (int q = 0; q < 4; ++q)
        gload16(gA + (size_t)(q * 8) * D_MODEL, smem + (w * 32 + q * 8) * 128);
#pragma unroll
    for (int q = 0; q < 3; ++q)
        gload16(gB + (size_t)(q * 8) * D_MODEL, smem + ABUF + (w * 24 + q * 8) * 128);
    __syncthreads();
    for (int it = 0; it < 12; ++it) {
        const char* cb = smem + (it & 1) * BUFSZ;
        if (it < 11) {
            char* nb = smem + ((it + 1) & 1) * BUFSZ;
            int k = (it + 1) * 64;
#pragma unroll
            for (int q = 0; q < 4; ++q)
                gload16(gA + (size_t)(q * 8) * D_MODEL + k, nb + (w * 32 + q * 8) * 128);
#pragma unroll
            for (int q = 0; q < 3; ++q)
                gload16(gB + (size_t)(q * 8) * D_MODEL + k, nb + ABUF + (w * 24 + q * 8) * 128);
        }
#pragma unroll
        for (int kk = 0; kk < 2; ++kk) {
            int sgb = kk * 4 + (l >> 4);
            bf16x8 af[4], bf[3];
#pragma unroll
            for (int mt = 0; mt < 4; ++mt) {
                int r = wm + mt * 16 + (l & 15);
                af[mt] = *(const bf16x8*)(cb + r * 128 + ((sgb ^ (r & 7)) * 16));
            }
#pragma unroll
            for (int nt = 0; nt < 3; ++nt) {
                int r = wn + nt * 16 + (l & 15);
                bf[nt] = *(const bf16x8*)(cb + ABUF + r * 128 + ((sgb ^ (r & 7)) * 16));
            }
#pragma unroll
            for (int mt = 0; mt < 4; ++mt)
#pragma unroll
                for (int nt = 0; nt < 3; ++nt)
                    acc[mt][nt] = __builtin_amdgcn_mfma_f32_16x16x32_bf16(af[mt], bf[nt], acc[mt][nt], 0, 0, 0);
        }
        __syncthreads();
    }
}

// gemm_in: u = xn @ W_in^T + b_in -> uTb bf16 [b][n][s] via LDS transpose
__global__ __launch_bounds__(256, 1) void gemm_in(const ushort_t* __restrict__ A,
                                                  const ushort_t* __restrict__ B,
                                                  const float* __restrict__ bias,
                                                  ushort_t* __restrict__ uTb) {
    __shared__ __align__(16) char smem[2 * BUFSZ];
    int tid = threadIdx.x;
    int w = tid >> 6, l = tid & 63;
    int bm = blockIdx.x * 128, bn = blockIdx.y * 96;
    int wm = (w & 1) * 64, wn = (w >> 1) * 48;
    f32x4 acc[4][3] = {};
    float biasv[3];
    gemm_core(A, B, bias, smem, tid, bm, bn, w, l, wm, wn, acc, biasv);

    ushort_t* T = (ushort_t*)smem;                 // [96][136] = 26112 B
#pragma unroll
    for (int mt = 0; mt < 4; ++mt)
#pragma unroll
        for (int nt = 0; nt < 3; ++nt)
#pragma unroll
            for (int i = 0; i < 4; ++i) {
                int n = wn + nt * 16 + (l & 15);
                int m = wm + mt * 16 + (l >> 4) * 4 + i;
                T[n * 136 + m] = f2bf(acc[mt][nt][i] + biasv[nt]);
            }
    __syncthreads();
    int b = bm >> 11, s0 = bm & 2047;
#pragma unroll
    for (int rep = 0; rep < 6; ++rep) {
        int idx = rep * 256 + tid;
        int row = idx >> 4, sg = idx & 15;
        uint4 v = *(const uint4*)&T[row * 136 + sg * 8];
        *(uint4*)(uTb + ((size_t)b * D_MODEL + bn + row) * SEQ + s0 + sg * 8) = v;
    }
}

// gemm_out: out = y @ W_out^T + b_out + resid, natural [m][n] fp32 store
__global__ __launch_bounds__(256, 1) void gemm_out(const ushort_t* __restrict__ A,
                                                   const ushort_t* __restrict__ B,
                                                   const float* __restrict__ bias,
                                                   const float* __restrict__ resid,
                                                   float* __restrict__ out) {
    __shared__ __align__(16) char smem[2 * BUFSZ];
    int tid = threadIdx.x;
    int w = tid >> 6, l = tid & 63;
    int bm = blockIdx.x * 128, bn = blockIdx.y * 96;
    int wm = (w & 1) * 64, wn = (w >> 1) * 48;
    f32x4 acc[4][3] = {};
    float biasv[3];
    gemm_core(A, B, bias, smem, tid, bm, bn, w, l, wm, wn, acc, biasv);

#pragma unroll
    for (int mt = 0; mt < 4; ++mt)
#pragma unroll
        for (int i = 0; i < 4; ++i) {
            int m = bm + wm + mt * 16 + (l >> 4) * 4 + i;
            const float* rp = resid + (size_t)m * D_MODEL + bn;
            float* op = out + (size_t)m * D_MODEL + bn;
#pragma unroll
            for (int nt = 0; nt < 3; ++nt) {
                int n = wn + nt * 16 + (l & 15);
                op[n] = acc[mt][nt][i] + biasv[nt] + rp[n];
            }
        }
}

// ---------------- scan as blocked matmuls (SSD-style), bf16 output ----------------
#define OFF_U  0
#define OFF_V  9216
#define OFF_T  18432
#define OFF_M  27648
#define OFF_H  36864
#define OFF_W  46080
#define OFF_SM 63488

__global__ __launch_bounds__(256) void scan_mm(const ushort_t* __restrict__ uTb,
                                               const float* __restrict__ log_A,
                                               const float* __restrict__ B_p,
                                               const float* __restrict__ C_p,
                                               const float* __restrict__ D_p,
                                               const float* __restrict__ log_dt,
                                               ushort_t* __restrict__ yTb) {
    __shared__ __align__(16) char smem[65024];
    ushort_t* Up = (ushort_t*)(smem + OFF_U);
    ushort_t* Vp = (ushort_t*)(smem + OFF_V);
    ushort_t* Tp = (ushort_t*)(smem + OFF_T);
    ushort_t* Mp = (ushort_t*)(smem + OFF_M);
    ushort_t* Hp = (ushort_t*)(smem + OFF_H);
    float*    Wp = (float*)(smem + OFF_W);
    float*    Kp = (float*)(smem + OFF_W);
    float*    aArr  = (float*)(smem + OFF_SM);
    float*    BbArr = aArr + 64;
    float*    CcArr = aArr + 128;
    float*    CBArr = aArr + 192;
    float*    Kc    = aArr + 256;

    int d   = blockIdx.x;
    int tid = threadIdx.x;
    int w   = tid >> 6, l = tid & 63;

    if (tid < 64) {
        int n = tid;
        float dt = __expf(log_dt[d]);
        float a  = -dt * __expf(log_A[d * 64 + n]);
        float Bb = B_p[d * 64 + n] * dt;
        float Cc = C_p[d * 64 + n];
        aArr[n] = a; BbArr[n] = Bb; CcArr[n] = Cc; CBArr[n] = Cc * Bb;
    }
    __syncthreads();

    {
        int tau = tid & 63, part = tid >> 6;
        float s = 0.f;
#pragma unroll
        for (int i = 0; i < 16; ++i) {
            int n = part * 16 + i;
            s += CBArr[n] * __expf((float)tau * aArr[n]);
        }
        Kp[part * 64 + tau] = s;
    }
    __syncthreads();
    if (tid < 64)
        Kc[tid] = Kp[tid] + Kp[64 + tid] + Kp[128 + tid] + Kp[192 + tid]
                + (tid == 0 ? D_p[d] : 0.f);
    __syncthreads();

    {
        int r = tid >> 2, seg = (tid & 3) * 16;
        float a = aArr[r], Bb = BbArr[r];
#pragma unroll
        for (int i = 0; i < 16; ++i) {
            int s = seg + i;
            Vp[r * 72 + s] = f2bf(Bb * __expf((float)(63 - s) * a));
        }
#pragma unroll
        for (int i = 0; i < 16; ++i) {
            int n = seg + i;
            Mp[r * 72 + n] = f2bf(CcArr[n] * __expf((float)(r + 1) * aArr[n]));
        }
#pragma unroll
        for (int i = 0; i < 16; ++i) {
            int s = seg + i;
            Tp[r * 72 + s] = (s <= r) ? f2bf(Kc[r - s]) : (ushort_t)0;
        }
        int col = r, bu = col >> 5, cu = col & 31;
        const ushort_t* usrc = uTb + ((size_t)bu * D_MODEL + d) * SEQ + cu * 64 + seg;
        *(uint4*)(Up + col * 72 + seg)     = *(const uint4*)(usrc);
        *(uint4*)(Up + col * 72 + seg + 8) = *(const uint4*)(usrc + 8);
    }
    __syncthreads();

    {
        int p0 = w * 16;
        f32x4 acc1[4] = {};
#pragma unroll
        for (int kk = 0; kk < 2; ++kk) {
            int koff = kk * 32 + (l >> 4) * 8;
            bf16x8 af = *(const bf16x8*)(Vp + (p0 + (l & 15)) * 72 + koff);
#pragma unroll
            for (int qt = 0; qt < 4; ++qt) {
                bf16x8 bf = *(const bf16x8*)(Up + (qt * 16 + (l & 15)) * 72 + koff);
                acc1[qt] = __builtin_amdgcn_mfma_f32_16x16x32_bf16(af, bf, acc1[qt], 0, 0, 0);
            }
        }
#pragma unroll
        for (int qt = 0; qt < 4; ++qt)
#pragma unroll
            for (int i = 0; i < 4; ++i)
                Wp[(qt * 16 + (l & 15)) * 68 + p0 + (l >> 4) * 4 + i] = acc1[qt][i];
    }
    __syncthreads();

    if (tid < 128) {
        int b2 = tid >> 6, n = tid & 63;
        float Ab64 = __expf(64.f * aArr[n]);
        float H = 0.f;
#pragma unroll
        for (int c = 0; c < 32; ++c) {
            int col = b2 * 32 + c;
            Hp[col * 72 + n] = f2bf(H);
            H = fmaf(Ab64, H, Wp[col * 68 + n]);
        }
    }
    __syncthreads();

    {
        int j0 = w * 16;
        f32x4 accY[4] = {};
#pragma unroll
        for (int kk = 0; kk < 2; ++kk) {
            int koff = kk * 32 + (l >> 4) * 8;
            bf16x8 at = *(const bf16x8*)(Tp + (j0 + (l & 15)) * 72 + koff);
            bf16x8 am = *(const bf16x8*)(Mp + (j0 + (l & 15)) * 72 + koff);
#pragma unroll
            for (int qt = 0; qt < 4; ++qt) {
                bf16x8 bu = *(const bf16x8*)(Up + (qt * 16 + (l & 15)) * 72 + koff);
                bf16x8 bh = *(const bf16x8*)(Hp + (qt * 16 + (l & 15)) * 72 + koff);
                accY[qt] = __builtin_amdgcn_mfma_f32_16x16x32_bf16(at, bu, accY[qt], 0, 0, 0);
                accY[qt] = __builtin_amdgcn_mfma_f32_16x16x32_bf16(am, bh, accY[qt], 0, 0, 0);
            }
        }
#pragma unroll
        for (int qt = 0; qt < 4; ++qt)
#pragma unroll
            for (int i = 0; i < 4; ++i)
                Wp[(qt * 16 + (l & 15)) * 68 + j0 + (l >> 4) * 4 + i] = accY[qt][i];
    }
    __syncthreads();

    {
        int col = tid >> 2, jseg = (tid & 3) * 16;
        int b3 = col >> 5, c3 = col & 31;
        ushort_t* dst = yTb + ((size_t)b3 * D_MODEL + d) * SEQ + c3 * 64 + jseg;
#pragma unroll
        for (int q = 0; q < 4; ++q) {
            float4 v = *(const float4*)(Wp + col * 68 + jseg + q * 4);
            ushort4 o = make_ushort4(f2bf(v.x), f2bf(v.y), f2bf(v.z), f2bf(v.w));
            *(ushort4*)(dst + q * 4) = o;
        }
    }
}

// ---------------- transpose: yTb bf16 [2][768][2048] -> yA bf16 [4096][768] ----------------
__global__ __launch_bounds__(256) void tcast_kernel(const ushort_t* __restrict__ yTb,
                                                    ushort_t* __restrict__ yA) {
    __shared__ ushort_t T3[64 * 72];
    int t = threadIdx.x;
    int s0 = blockIdx.x * 64, d0 = blockIdx.y * 64, b = blockIdx.z;
    int dl = t >> 2, sq = (t & 3) * 16;
    const ushort_t* src = yTb + ((size_t)b * D_MODEL + d0 + dl) * SEQ + s0 + sq;
    ushort_t tmp[16];
    *(uint4*)tmp       = *(const uint4*)src;
    *(uint4*)(tmp + 8) = *(const uint4*)(src + 8);
#pragma unroll
    for (int i = 0; i < 16; ++i)
        T3[(sq + i) * 72 + dl] = tmp[i];
    __syncthreads();
    int sl = t >> 2, dseg = (t & 3) * 16;
    ushort_t* dst = yA + ((size_t)b * SEQ + s0 + sl) * D_MODEL + d0 + dseg;
    *(uint4*)dst       = *(const uint4*)&T3[sl * 72 + dseg];
    *(uint4*)(dst + 8) = *(const uint4*)&T3[sl * 72 + dseg + 8];
}

extern "C" void kernel_launch(void* const* d_in, const int* in_sizes, int n_in,
                              void* d_out, int out_size, void* d_ws, size_t ws_size,
                              hipStream_t stream) {
    const float* x        = (const float*)d_in[0];
    const float* ln_gamma = (const float*)d_in[1];
    const float* ln_beta  = (const float*)d_in[2];
    const float* W_in     = (const float*)d_in[3];
    const float* b_in     = (const float*)d_in[4];
    const float* log_A    = (const float*)d_in[5];
    const float* B_p      = (const float*)d_in[6];
    const float* C_p      = (const float*)d_in[7];
    const float* D_p      = (const float*)d_in[8];
    const float* log_dt   = (const float*)d_in[9];
    const float* W_out    = (const float*)d_in[10];
    const float* b_out    = (const float*)d_in[11];
    float* out = (float*)d_out;

    char* ws = (char*)d_ws;
    ushort_t* uTb   = (ushort_t*)(ws + 0);            // 6291456 B bf16 [2][768][2048]
    ushort_t* yTb   = (ushort_t*)(ws + 6291456);      // 6291456 B bf16 [2][768][2048]
    ushort_t* xnb   = (ushort_t*)(ws + 12582912);     // 6291456 B (reused as yA)
    ushort_t* yA    = xnb;
    ushort_t* Winb  = (ushort_t*)(ws + 18874368);     // 1179648 B
    ushort_t* Woutb = (ushort_t*)(ws + 20054016);     // 1179648 B

    pre_kernel<<<dim3(1024 + 1152), 256, 0, stream>>>(x, ln_gamma, ln_beta, xnb,
                                                      W_in, W_out, Winb, Woutb);
    gemm_in<<<dim3(M_TOTAL / 128, D_MODEL / 96), 256, 0, stream>>>(xnb, Winb, b_in, uTb);
    scan_mm<<<dim3(D_MODEL), 256, 0, stream>>>(uTb, log_A, B_p, C_p, D_p, log_dt, yTb);
    tcast_kernel<<<dim3(SEQ / 64, D_MODEL / 64, BATCH), 256, 0, stream>>>(yTb, yA);
    gemm_out<<<dim3(M_TOTAL / 128, D_MODEL / 96), 256, 0, stream>>>(yA, Woutb, b_out, x, out);
}